// Round 8
// baseline (156.883 us; speedup 1.0000x reference)
//
#include <hip/hip_runtime.h>
#include <math.h>

#define NCLS 20
#define CH 64
#define NPIX (384*384)
#define BATCH 2
#define MINSZ 5000
#define EPSV 1e-6f
#define NCHUNK 16
#define NBLK (BATCH*NPIX/256)      // 1152
#define BLKPERB (NPIX/256)         // 576
#define PSTRIDE 4160               // 4096 sxx + 64 sums
#define XSTR 72                    // base channel-major stride (elems)
#define ROWOFF(c) ((c)*XSTR + ((c)>>3)*8)   // +8 elems pad every 8 rows: spreads banks

typedef __attribute__((ext_vector_type(8))) __bf16 bf16x8;
typedef __attribute__((ext_vector_type(4))) float  f32x4;

static __device__ inline unsigned short f2bf(float f) {
    unsigned u = __builtin_bit_cast(unsigned, f);
    return (unsigned short)((u + 0x7fffu + ((u >> 16) & 1u)) >> 16);
}
static __device__ inline float bf2f(unsigned us) {
    unsigned u = us << 16;
    return __builtin_bit_cast(float, u);
}

// ---------------- K1: per-block class histogram ----------------
__global__ void k_hist(const int* __restrict__ seg, int* __restrict__ hist) {
    __shared__ int h[NCLS];
    int t = threadIdx.x;
    if (t < NCLS) h[t] = 0;
    __syncthreads();
    int k = seg[blockIdx.x * 256 + t];
    atomicAdd(&h[k], 1);
    __syncthreads();
    if (t < NCLS) hist[blockIdx.x * NCLS + t] = h[t];
}

// ---------------- K2: fused counts + parallel scan ----------------
__global__ void __launch_bounds__(256) k_scanall(const int* __restrict__ hist,
        int* __restrict__ counts, int* __restrict__ blockbase, int* __restrict__ offsets) {
    int bk = blockIdx.x;
    int b = bk / NCLS, k = bk % NCLS;
    int t = threadIdx.x;
    __shared__ int sh[BLKPERB];
    __shared__ int part[NCLS][12];
    __shared__ int ctot[NCLS];
    __shared__ int tpA[256], tpB[256];
    __shared__ int soff;

    const int* hb = hist + (size_t)b * BLKPERB * NCLS;
    for (int e = t; e < BLKPERB; e += 256) sh[e] = hb[e * NCLS + k];
    if (t < NCLS * 12) {
        int kk = t / 12, sub = t % 12;
        int s = 0;
        #pragma unroll 8
        for (int e = sub * 48; e < sub * 48 + 48; ++e) s += hb[e * NCLS + kk];
        part[kk][sub] = s;
    }
    __syncthreads();
    if (t < NCLS) {
        int s = 0;
        #pragma unroll
        for (int j = 0; j < 12; ++j) s += part[t][j];
        ctot[t] = s;
    }
    __syncthreads();
    if (t == 0) {
        int off = b * NPIX;
        for (int kk = 0; kk < k; ++kk) off += ctot[kk];
        soff = off;
        offsets[bk] = off;
        counts[bk] = ctot[k];
    }
    int s0 = 0, s1 = 0, s2 = 0;
    if (t < 192) {
        s0 = sh[3*t];
        s1 = s0 + sh[3*t + 1];
        s2 = s1 + sh[3*t + 2];
    }
    int mytot = (t < 192) ? s2 : 0;
    tpA[t] = mytot;
    __syncthreads();
    tpB[t] = tpA[t] + ((t >= 1)   ? tpA[t-1]   : 0); __syncthreads();
    tpA[t] = tpB[t] + ((t >= 2)   ? tpB[t-2]   : 0); __syncthreads();
    tpB[t] = tpA[t] + ((t >= 4)   ? tpA[t-4]   : 0); __syncthreads();
    tpA[t] = tpB[t] + ((t >= 8)   ? tpB[t-8]   : 0); __syncthreads();
    tpB[t] = tpA[t] + ((t >= 16)  ? tpA[t-16]  : 0); __syncthreads();
    tpA[t] = tpB[t] + ((t >= 32)  ? tpB[t-32]  : 0); __syncthreads();
    tpB[t] = tpA[t] + ((t >= 64)  ? tpA[t-64]  : 0); __syncthreads();
    tpA[t] = tpB[t] + ((t >= 128) ? tpB[t-128] : 0); __syncthreads();
    if (t < 192) {
        int excl = soff + tpA[t] - mytot;
        int* bb = blockbase + ((size_t)b * BLKPERB) * NCLS + k;
        bb[(3*t    ) * NCLS] = excl;
        bb[(3*t + 1) * NCLS] = excl + s0;
        bb[(3*t + 2) * NCLS] = excl + s1;
    }
}

// ---------------- K3: LDS-staged class-sorted scatter -> bf16 gathered ----------------
__global__ void __launch_bounds__(256) k_scatter(const float* __restrict__ x, const int* __restrict__ seg,
                          const int* __restrict__ blockbase, unsigned short* __restrict__ gathered) {
    __shared__ float tile[256 * 33];
    __shared__ int wcnt[4][NCLS];
    __shared__ int sblk[NCLS];
    __shared__ int drow[256];
    int t = threadIdx.x;
    int blk = blockIdx.x;
    int base = blk * 256;
    int b = base / NPIX;
    int n = (base % NPIX) + t;
    int k = seg[base + t];
    int wave = t >> 6, lane = t & 63;

    int riw = 0;
    for (int cls = 0; cls < NCLS; ++cls) {
        unsigned long long m = __ballot(k == cls);
        if (lane == 0) wcnt[wave][cls] = __popcll(m);
        if (k == cls) riw = __popcll(m & ((1ull << lane) - 1ull));
    }
    __syncthreads();
    if (t < NCLS) {
        int s = 0;
        for (int c = 0; c < t; ++c) s += wcnt[0][c] + wcnt[1][c] + wcnt[2][c] + wcnt[3][c];
        sblk[t] = s;
    }
    __syncthreads();
    int rib = riw;
    for (int w = 0; w < 4; ++w) if (w < wave) rib += wcnt[w][k];
    int slot = sblk[k] + rib;
    drow[slot] = blockbase[blk * NCLS + k] + rib;
    const float* xb = x + (size_t)b * CH * NPIX + n;

    for (int ph = 0; ph < 2; ++ph) {
        __syncthreads();
        #pragma unroll 8
        for (int c = 0; c < 32; ++c)
            tile[slot * 33 + c] = xb[(size_t)(ph * 32 + c) * NPIX];
        __syncthreads();
        #pragma unroll 8
        for (int it = 0; it < 16; ++it) {
            int f = it * 256 + t;
            int r = f >> 4, c2 = f & 15;
            float a = tile[r * 33 + c2 * 2];
            float bq = tile[r * 33 + c2 * 2 + 1];
            unsigned pk = (unsigned)f2bf(a) | ((unsigned)f2bf(bq) << 16);
            *(unsigned*)(gathered + (size_t)drow[r] * CH + ph * 32 + c2 * 2) = pk;
        }
    }
}

// ---------------- K4: per-(b,k,chunk) sxx via bf16 MFMA ----------------
__global__ void __launch_bounds__(256) k_gemm(const unsigned short* __restrict__ gathered,
        const int* __restrict__ counts, const int* __restrict__ offsets,
        float* __restrict__ partials) {
    __shared__ __align__(16) unsigned short xt[64 * XSTR + 7 * 8];
    __shared__ float wsum[4][CH];
    int id = blockIdx.x;
    int chunk = id % NCHUNK;
    int bk = id / NCHUNK;
    int cnt = counts[bk];
    int off = offsets[bk];
    int csz = (cnt + NCHUNK - 1) / NCHUNK;
    int p0 = chunk * csz;
    int pend = min(cnt, p0 + csz);
    int t = threadIdx.x;
    int w = t >> 6, l = t & 63, g = l >> 4, c15 = l & 15;
    int cg = t & 7;
    int ppair = t >> 3;

    f32x4 acc[4];
    #pragma unroll
    for (int nb = 0; nb < 4; ++nb) { f32x4 z = {0.f,0.f,0.f,0.f}; acc[nb] = z; }
    float ssum[8] = {0.f,0.f,0.f,0.f,0.f,0.f,0.f,0.f};

    for (int tp = p0; tp < pend; tp += 64) {
        __syncthreads();
        {
            int gp0 = tp + 2 * ppair, gp1 = gp0 + 1;
            uint4 v0 = make_uint4(0u,0u,0u,0u), v1 = make_uint4(0u,0u,0u,0u);
            if (gp0 < pend) v0 = *(const uint4*)(gathered + (size_t)(off + gp0) * CH + cg * 8);
            if (gp1 < pend) v1 = *(const uint4*)(gathered + (size_t)(off + gp1) * CH + cg * 8);
            unsigned a0[4] = {v0.x, v0.y, v0.z, v0.w};
            unsigned a1[4] = {v1.x, v1.y, v1.z, v1.w};
            #pragma unroll
            for (int q = 0; q < 4; ++q) {
                unsigned lo0 = a0[q] & 0xffffu, hi0 = a0[q] >> 16;
                unsigned lo1 = a1[q] & 0xffffu, hi1 = a1[q] >> 16;
                ssum[2*q]   += bf2f(lo0) + bf2f(lo1);
                ssum[2*q+1] += bf2f(hi0) + bf2f(hi1);
                int ch0 = 8 * cg + 2 * q;
                *(unsigned*)(xt + ROWOFF(ch0)     + 2 * ppair) = lo0 | (lo1 << 16);
                *(unsigned*)(xt + ROWOFF(ch0 + 1) + 2 * ppair) = hi0 | (hi1 << 16);
            }
        }
        __syncthreads();
        #pragma unroll
        for (int kc = 0; kc < 2; ++kc) {
            bf16x8 fr0 = *(const bf16x8*)(xt + ROWOFF( 0 + c15) + kc * 32 + 8 * g);
            bf16x8 fr1 = *(const bf16x8*)(xt + ROWOFF(16 + c15) + kc * 32 + 8 * g);
            bf16x8 fr2 = *(const bf16x8*)(xt + ROWOFF(32 + c15) + kc * 32 + 8 * g);
            bf16x8 fr3 = *(const bf16x8*)(xt + ROWOFF(48 + c15) + kc * 32 + 8 * g);
            bf16x8 fa;
            if      (w == 0) fa = fr0;
            else if (w == 1) fa = fr1;
            else if (w == 2) fa = fr2;
            else             fa = fr3;
            acc[0] = __builtin_amdgcn_mfma_f32_16x16x32_bf16(fa, fr0, acc[0], 0, 0, 0);
            acc[1] = __builtin_amdgcn_mfma_f32_16x16x32_bf16(fa, fr1, acc[1], 0, 0, 0);
            acc[2] = __builtin_amdgcn_mfma_f32_16x16x32_bf16(fa, fr2, acc[2], 0, 0, 0);
            acc[3] = __builtin_amdgcn_mfma_f32_16x16x32_bf16(fa, fr3, acc[3], 0, 0, 0);
        }
    }

    float* pout = partials + (size_t)id * PSTRIDE;
    #pragma unroll
    for (int nb = 0; nb < 4; ++nb)
        #pragma unroll
        for (int r = 0; r < 4; ++r)
            pout[(16*w + 4*g + r) * 64 + 16*nb + c15] = acc[nb][r];

    #pragma unroll
    for (int o = 8; o < 64; o <<= 1)
        #pragma unroll
        for (int j = 0; j < 8; ++j) ssum[j] += __shfl_xor(ssum[j], o);
    if (l < 8) {
        #pragma unroll
        for (int j = 0; j < 8; ++j) wsum[w][l * 8 + j] = ssum[j];
    }
    __syncthreads();
    if (t < CH) pout[4096 + t] = wsum[0][t] + wsum[1][t] + wsum[2][t] + wsum[3][t];
}

// ---------------- K4b: parallel reduce of chunk partials ----------------
__global__ void __launch_bounds__(256) k_reduce(const float* __restrict__ partials,
        float* __restrict__ sxxred) {
    int id = blockIdx.x;             // bk*17 + slice
    int bk = id / 17, slice = id % 17;
    int t = threadIdx.x;
    const float* pp = partials + (size_t)bk * NCHUNK * PSTRIDE;
    if (slice < 16) {
        int e = slice * 256 + t;
        float v = 0.f;
        #pragma unroll
        for (int ch = 0; ch < NCHUNK; ++ch) v += pp[(size_t)ch * PSTRIDE + e];
        sxxred[(size_t)bk * PSTRIDE + e] = v;
    } else if (t < CH) {
        float v = 0.f;
        #pragma unroll
        for (int ch = 0; ch < NCHUNK; ++ch) v += pp[(size_t)ch * PSTRIDE + 4096 + t];
        sxxred[(size_t)bk * PSTRIDE + 4096 + t] = v;
    }
}

// ---------------- K5: one-wave register-resident solve ----------------
// Lane d owns column d of cov in regs (Mc[64]); rhs replicated in all lanes.
// Forward elim: f-vector = row j = each lane's own Mc[j] (Schur symmetry)
//   -> publish is ONE ds_write_b32/iter. Back-sub on rhs with frozen U.
__global__ void __launch_bounds__(64) k_solve(const float* __restrict__ sxxred,
        const int* __restrict__ counts, const float* __restrict__ pattern,
        float* __restrict__ params) {
    int bk = blockIdx.x;
    int lane = threadIdx.x;          // 0..63, one wave
    __shared__ __align__(16) float srow[2][64];
    __shared__ __align__(16) float sfb[2][64];
    __shared__ float spinv[64];
    __shared__ float ssm[64];
    __shared__ float spat[64];

    const float* pp = sxxred + (size_t)bk * PSTRIDE;
    int cnt = counts[bk];
    float inv = 1.0f / fmaxf((float)cnt, 1.0f);
    ssm[lane] = pp[4096 + lane];
    spat[lane] = pattern[lane];
    __syncthreads();

    float Mc[64];    // column `lane` of cov
    float rhs[64];   // replicated rhs
    float mean_d = ssm[lane] * inv;
    #pragma unroll
    for (int r = 0; r < 64; ++r) {
        float s = pp[r * 64 + lane];             // coalesced row read -> col element
        float cov = s * inv - (ssm[r] * inv) * mean_d;
        Mc[r] = cov + ((r == lane) ? EPSV : 0.f);
        rhs[r] = spat[r];
    }

    // ---- forward elimination (row j via symmetry: one b32 write/iter) ----
    #pragma unroll
    for (int j = 0; j < 64; ++j) {
        srow[j & 1][lane] = Mc[j];               // publish row j
        __syncthreads();
        float pinv = 1.0f / srow[j & 1][j];
        if (lane == 0) spinv[j] = pinv;
        #pragma unroll
        for (int i = (j + 1) >> 2; i < 16; ++i) {
            float4 rv = *((const float4*)srow[j & 1] + i);
            float rvq[4] = {rv.x, rv.y, rv.z, rv.w};
            #pragma unroll
            for (int q = 0; q < 4; ++q) {
                int r = 4 * i + q;
                if (r > j) {
                    float tf = rvq[q] * pinv;
                    Mc[r]  = fmaf(-tf, Mc[j],  Mc[r]);
                    rhs[r] = fmaf(-tf, rhs[j], rhs[r]);
                }
            }
        }
        __syncthreads();
    }

    // ---- back-substitution on rhs (frozen U; column j upper from lane j) ----
    #pragma unroll
    for (int jj = 0; jj < 64; ++jj) {
        int j = 63 - jj;
        int nch = (j + 3) >> 2;                  // chunks covering r < j
        if (lane == j) {
            #pragma unroll
            for (int i = 0; i < 16; ++i) {
                if (i < nch)
                    *((float4*)sfb[jj & 1] + i) =
                        make_float4(Mc[4*i], Mc[4*i+1], Mc[4*i+2], Mc[4*i+3]);
            }
        }
        __syncthreads();
        float tj = rhs[j] * spinv[j];            // = w_j
        #pragma unroll
        for (int i = 0; i < 16; ++i) {
            if (i < nch) {
                float4 rv = *((const float4*)sfb[jj & 1] + i);
                float rvq[4] = {rv.x, rv.y, rv.z, rv.w};
                #pragma unroll
                for (int q = 0; q < 4; ++q) {
                    int r = 4 * i + q;
                    if (r < j) rhs[r] = fmaf(-rvq[q], tj, rhs[r]);
                }
            }
        }
    }

    // ---- epilogue (all lanes redundant) ----
    __syncthreads();
    float dp = 0.f, bias = 0.f;
    #pragma unroll
    for (int r = 0; r < 64; ++r) {
        float wr = rhs[r] * spinv[r];
        dp   = fmaf(spat[r], wr, dp);
        bias = fmaf(ssm[r] * inv, wr, bias);
        rhs[r] = wr;
    }
    float denom = sqrtf(dp);
    float valid = (cnt >= MINSZ) ? 1.0f : 0.0f;
    float scale = (denom > 0.f) ? (valid / denom) : 0.0f;
    if (lane == 0) {
        #pragma unroll
        for (int r = 0; r < 64; ++r) params[bk*66 + r] = rhs[r] * scale;
        params[bk*66 + 64] = bias * scale;
        params[bk*66 + 65] = 0.f;
    }
}

// ---------------- K6: fused per-pixel score ----------------
__global__ void k_score(const float* __restrict__ x, const int* __restrict__ seg,
                        const float* __restrict__ params, float* __restrict__ out) {
    __shared__ float pw[NCLS][66];
    int t = threadIdx.x;
    int base = blockIdx.x * 256;
    int b = base / NPIX;
    for (int e = t; e < NCLS*66; e += 256)
        ((float*)pw)[e] = params[b*NCLS*66 + e];
    __syncthreads();

    int k = seg[base + t];
    int n = (base % NPIX) + t;
    const float* xb = x + (size_t)b * CH * NPIX + n;
    float a0 = 0.f, a1 = 0.f, a2 = 0.f, a3 = 0.f;
    #pragma unroll
    for (int c = 0; c < CH; c += 4) {
        a0 += xb[(size_t)(c+0) * NPIX] * pw[k][c+0];
        a1 += xb[(size_t)(c+1) * NPIX] * pw[k][c+1];
        a2 += xb[(size_t)(c+2) * NPIX] * pw[k][c+2];
        a3 += xb[(size_t)(c+3) * NPIX] * pw[k][c+3];
    }
    out[base + t] = (a0 + a1) + (a2 + a3) - pw[k][64];
}

// ---------------- launch ----------------
extern "C" void kernel_launch(void* const* d_in, const int* in_sizes, int n_in,
                              void* d_out, int out_size, void* d_ws, size_t ws_size,
                              hipStream_t stream) {
    const float* x       = (const float*)d_in[0];   // (B,C,H,W) fp32
    const float* pattern = (const float*)d_in[1];   // (C,) fp32
    const int*   seg     = (const int*)d_in[2];     // (B,H,W) int32
    float* out = (float*)d_out;

    unsigned short* gathered = (unsigned short*)d_ws;                  // B*N*CH bf16
    float* partials = (float*)(gathered + (size_t)BATCH * NPIX * CH);  // B*K*NCHUNK*PSTRIDE
    float* sxxred   = partials + (size_t)BATCH * NCLS * NCHUNK * PSTRIDE; // B*K*PSTRIDE
    float* params   = sxxred + (size_t)BATCH * NCLS * PSTRIDE;         // B*K*66
    int* hist      = (int*)(params + BATCH * NCLS * 66);               // NBLK*NCLS
    int* blockbase = hist + NBLK * NCLS;                               // NBLK*NCLS
    int* counts    = blockbase + NBLK * NCLS;                          // B*K
    int* offsets   = counts + BATCH * NCLS;                            // B*K

    k_hist   <<<NBLK,               256, 0, stream>>>(seg, hist);
    k_scanall<<<BATCH*NCLS,         256, 0, stream>>>(hist, counts, blockbase, offsets);
    k_scatter<<<NBLK,               256, 0, stream>>>(x, seg, blockbase, gathered);
    k_gemm   <<<BATCH*NCLS*NCHUNK,  256, 0, stream>>>(gathered, counts, offsets, partials);
    k_reduce <<<BATCH*NCLS*17,      256, 0, stream>>>(partials, sxxred);
    k_solve  <<<BATCH*NCLS,          64, 0, stream>>>(sxxred, counts, pattern, params);
    k_score  <<<NBLK,               256, 0, stream>>>(x, seg, params, out);
}

// Round 9
// 109.128 us; speedup vs baseline: 1.4376x; 1.4376x over previous
//
#include <hip/hip_runtime.h>
#include <math.h>

#define NCLS 20
#define CH 64
#define NPIX (384*384)
#define BATCH 2
#define MINSZ 5000
#define EPSV 1e-6f
#define NCHUNK 16
#define NBLK (BATCH*NPIX/256)      // 1152
#define BLKPERB (NPIX/256)         // 576
#define PSTRIDE 4160               // 4096 sxx + 64 sums
#define XSTR 72                    // base channel-major stride (elems)
#define ROWOFF(c) ((c)*XSTR + ((c)>>3)*8)   // +8 elems pad every 8 rows: spreads banks

typedef __attribute__((ext_vector_type(8))) __bf16 bf16x8;
typedef __attribute__((ext_vector_type(4))) float  f32x4;

static __device__ inline unsigned short f2bf(float f) {
    unsigned u = __builtin_bit_cast(unsigned, f);
    return (unsigned short)((u + 0x7fffu + ((u >> 16) & 1u)) >> 16);
}
static __device__ inline float bf2f(unsigned us) {
    unsigned u = us << 16;
    return __builtin_bit_cast(float, u);
}

// ---------------- K1: per-block class histogram ----------------
__global__ void k_hist(const int* __restrict__ seg, int* __restrict__ hist) {
    __shared__ int h[NCLS];
    int t = threadIdx.x;
    if (t < NCLS) h[t] = 0;
    __syncthreads();
    int k = seg[blockIdx.x * 256 + t];
    atomicAdd(&h[k], 1);
    __syncthreads();
    if (t < NCLS) hist[blockIdx.x * NCLS + t] = h[t];
}

// ---------------- K2: fused counts + parallel scan ----------------
__global__ void __launch_bounds__(256) k_scanall(const int* __restrict__ hist,
        int* __restrict__ counts, int* __restrict__ blockbase, int* __restrict__ offsets) {
    int bk = blockIdx.x;
    int b = bk / NCLS, k = bk % NCLS;
    int t = threadIdx.x;
    __shared__ int sh[BLKPERB];
    __shared__ int part[NCLS][12];
    __shared__ int ctot[NCLS];
    __shared__ int tpA[256], tpB[256];
    __shared__ int soff;

    const int* hb = hist + (size_t)b * BLKPERB * NCLS;
    for (int e = t; e < BLKPERB; e += 256) sh[e] = hb[e * NCLS + k];
    if (t < NCLS * 12) {
        int kk = t / 12, sub = t % 12;
        int s = 0;
        #pragma unroll 8
        for (int e = sub * 48; e < sub * 48 + 48; ++e) s += hb[e * NCLS + kk];
        part[kk][sub] = s;
    }
    __syncthreads();
    if (t < NCLS) {
        int s = 0;
        #pragma unroll
        for (int j = 0; j < 12; ++j) s += part[t][j];
        ctot[t] = s;
    }
    __syncthreads();
    if (t == 0) {
        int off = b * NPIX;
        for (int kk = 0; kk < k; ++kk) off += ctot[kk];
        soff = off;
        offsets[bk] = off;
        counts[bk] = ctot[k];
    }
    int s0 = 0, s1 = 0, s2 = 0;
    if (t < 192) {
        s0 = sh[3*t];
        s1 = s0 + sh[3*t + 1];
        s2 = s1 + sh[3*t + 2];
    }
    int mytot = (t < 192) ? s2 : 0;
    tpA[t] = mytot;
    __syncthreads();
    tpB[t] = tpA[t] + ((t >= 1)   ? tpA[t-1]   : 0); __syncthreads();
    tpA[t] = tpB[t] + ((t >= 2)   ? tpB[t-2]   : 0); __syncthreads();
    tpB[t] = tpA[t] + ((t >= 4)   ? tpA[t-4]   : 0); __syncthreads();
    tpA[t] = tpB[t] + ((t >= 8)   ? tpB[t-8]   : 0); __syncthreads();
    tpB[t] = tpA[t] + ((t >= 16)  ? tpA[t-16]  : 0); __syncthreads();
    tpA[t] = tpB[t] + ((t >= 32)  ? tpB[t-32]  : 0); __syncthreads();
    tpB[t] = tpA[t] + ((t >= 64)  ? tpA[t-64]  : 0); __syncthreads();
    tpA[t] = tpB[t] + ((t >= 128) ? tpB[t-128] : 0); __syncthreads();
    if (t < 192) {
        int excl = soff + tpA[t] - mytot;
        int* bb = blockbase + ((size_t)b * BLKPERB) * NCLS + k;
        bb[(3*t    ) * NCLS] = excl;
        bb[(3*t + 1) * NCLS] = excl + s0;
        bb[(3*t + 2) * NCLS] = excl + s1;
    }
}

// ---------------- K3: LDS-staged class-sorted scatter -> bf16 gathered ----------------
__global__ void __launch_bounds__(256) k_scatter(const float* __restrict__ x, const int* __restrict__ seg,
                          const int* __restrict__ blockbase, unsigned short* __restrict__ gathered) {
    __shared__ float tile[256 * 33];
    __shared__ int wcnt[4][NCLS];
    __shared__ int sblk[NCLS];
    __shared__ int drow[256];
    int t = threadIdx.x;
    int blk = blockIdx.x;
    int base = blk * 256;
    int b = base / NPIX;
    int n = (base % NPIX) + t;
    int k = seg[base + t];
    int wave = t >> 6, lane = t & 63;

    int riw = 0;
    for (int cls = 0; cls < NCLS; ++cls) {
        unsigned long long m = __ballot(k == cls);
        if (lane == 0) wcnt[wave][cls] = __popcll(m);
        if (k == cls) riw = __popcll(m & ((1ull << lane) - 1ull));
    }
    __syncthreads();
    if (t < NCLS) {
        int s = 0;
        for (int c = 0; c < t; ++c) s += wcnt[0][c] + wcnt[1][c] + wcnt[2][c] + wcnt[3][c];
        sblk[t] = s;
    }
    __syncthreads();
    int rib = riw;
    for (int w = 0; w < 4; ++w) if (w < wave) rib += wcnt[w][k];
    int slot = sblk[k] + rib;
    drow[slot] = blockbase[blk * NCLS + k] + rib;
    const float* xb = x + (size_t)b * CH * NPIX + n;

    for (int ph = 0; ph < 2; ++ph) {
        __syncthreads();
        #pragma unroll 8
        for (int c = 0; c < 32; ++c)
            tile[slot * 33 + c] = xb[(size_t)(ph * 32 + c) * NPIX];
        __syncthreads();
        #pragma unroll 8
        for (int it = 0; it < 16; ++it) {
            int f = it * 256 + t;
            int r = f >> 4, c2 = f & 15;
            float a = tile[r * 33 + c2 * 2];
            float bq = tile[r * 33 + c2 * 2 + 1];
            unsigned pk = (unsigned)f2bf(a) | ((unsigned)f2bf(bq) << 16);
            *(unsigned*)(gathered + (size_t)drow[r] * CH + ph * 32 + c2 * 2) = pk;
        }
    }
}

// ---------------- K4: per-(b,k,chunk) sxx via bf16 MFMA ----------------
__global__ void __launch_bounds__(256) k_gemm(const unsigned short* __restrict__ gathered,
        const int* __restrict__ counts, const int* __restrict__ offsets,
        float* __restrict__ partials) {
    __shared__ __align__(16) unsigned short xt[64 * XSTR + 7 * 8];
    __shared__ float wsum[4][CH];
    int id = blockIdx.x;
    int chunk = id % NCHUNK;
    int bk = id / NCHUNK;
    int cnt = counts[bk];
    int off = offsets[bk];
    int csz = (cnt + NCHUNK - 1) / NCHUNK;
    int p0 = chunk * csz;
    int pend = min(cnt, p0 + csz);
    int t = threadIdx.x;
    int w = t >> 6, l = t & 63, g = l >> 4, c15 = l & 15;
    int cg = t & 7;
    int ppair = t >> 3;

    f32x4 acc[4];
    #pragma unroll
    for (int nb = 0; nb < 4; ++nb) { f32x4 z = {0.f,0.f,0.f,0.f}; acc[nb] = z; }
    float ssum[8] = {0.f,0.f,0.f,0.f,0.f,0.f,0.f,0.f};

    for (int tp = p0; tp < pend; tp += 64) {
        __syncthreads();
        {
            int gp0 = tp + 2 * ppair, gp1 = gp0 + 1;
            uint4 v0 = make_uint4(0u,0u,0u,0u), v1 = make_uint4(0u,0u,0u,0u);
            if (gp0 < pend) v0 = *(const uint4*)(gathered + (size_t)(off + gp0) * CH + cg * 8);
            if (gp1 < pend) v1 = *(const uint4*)(gathered + (size_t)(off + gp1) * CH + cg * 8);
            unsigned a0[4] = {v0.x, v0.y, v0.z, v0.w};
            unsigned a1[4] = {v1.x, v1.y, v1.z, v1.w};
            #pragma unroll
            for (int q = 0; q < 4; ++q) {
                unsigned lo0 = a0[q] & 0xffffu, hi0 = a0[q] >> 16;
                unsigned lo1 = a1[q] & 0xffffu, hi1 = a1[q] >> 16;
                ssum[2*q]   += bf2f(lo0) + bf2f(lo1);
                ssum[2*q+1] += bf2f(hi0) + bf2f(hi1);
                int ch0 = 8 * cg + 2 * q;
                *(unsigned*)(xt + ROWOFF(ch0)     + 2 * ppair) = lo0 | (lo1 << 16);
                *(unsigned*)(xt + ROWOFF(ch0 + 1) + 2 * ppair) = hi0 | (hi1 << 16);
            }
        }
        __syncthreads();
        #pragma unroll
        for (int kc = 0; kc < 2; ++kc) {
            bf16x8 fr0 = *(const bf16x8*)(xt + ROWOFF( 0 + c15) + kc * 32 + 8 * g);
            bf16x8 fr1 = *(const bf16x8*)(xt + ROWOFF(16 + c15) + kc * 32 + 8 * g);
            bf16x8 fr2 = *(const bf16x8*)(xt + ROWOFF(32 + c15) + kc * 32 + 8 * g);
            bf16x8 fr3 = *(const bf16x8*)(xt + ROWOFF(48 + c15) + kc * 32 + 8 * g);
            bf16x8 fa;
            if      (w == 0) fa = fr0;
            else if (w == 1) fa = fr1;
            else if (w == 2) fa = fr2;
            else             fa = fr3;
            acc[0] = __builtin_amdgcn_mfma_f32_16x16x32_bf16(fa, fr0, acc[0], 0, 0, 0);
            acc[1] = __builtin_amdgcn_mfma_f32_16x16x32_bf16(fa, fr1, acc[1], 0, 0, 0);
            acc[2] = __builtin_amdgcn_mfma_f32_16x16x32_bf16(fa, fr2, acc[2], 0, 0, 0);
            acc[3] = __builtin_amdgcn_mfma_f32_16x16x32_bf16(fa, fr3, acc[3], 0, 0, 0);
        }
    }

    float* pout = partials + (size_t)id * PSTRIDE;
    #pragma unroll
    for (int nb = 0; nb < 4; ++nb)
        #pragma unroll
        for (int r = 0; r < 4; ++r)
            pout[(16*w + 4*g + r) * 64 + 16*nb + c15] = acc[nb][r];

    #pragma unroll
    for (int o = 8; o < 64; o <<= 1)
        #pragma unroll
        for (int j = 0; j < 8; ++j) ssum[j] += __shfl_xor(ssum[j], o);
    if (l < 8) {
        #pragma unroll
        for (int j = 0; j < 8; ++j) wsum[w][l * 8 + j] = ssum[j];
    }
    __syncthreads();
    if (t < CH) pout[4096 + t] = wsum[0][t] + wsum[1][t] + wsum[2][t] + wsum[3][t];
}

// ---------------- K4b: parallel reduce of chunk partials ----------------
__global__ void __launch_bounds__(256) k_reduce(const float* __restrict__ partials,
        float* __restrict__ sxxred) {
    int id = blockIdx.x;             // bk*17 + slice
    int bk = id / 17, slice = id % 17;
    int t = threadIdx.x;
    const float* pp = partials + (size_t)bk * NCHUNK * PSTRIDE;
    if (slice < 16) {
        int e = slice * 256 + t;
        float v = 0.f;
        #pragma unroll
        for (int ch = 0; ch < NCHUNK; ++ch) v += pp[(size_t)ch * PSTRIDE + e];
        sxxred[(size_t)bk * PSTRIDE + e] = v;
    } else if (t < CH) {
        float v = 0.f;
        #pragma unroll
        for (int ch = 0; ch < NCHUNK; ++ch) v += pp[(size_t)ch * PSTRIDE + 4096 + t];
        sxxred[(size_t)bk * PSTRIDE + 4096 + t] = v;
    }
}

// ---------------- K5: one-wave register-resident solve (lean state) ----------------
// Lane d owns column d of cov in 64 VGPRs; rhs is DISTRIBUTED (1 scalar/lane).
// Forward elim (symmetric Schur): publish row j (1 b32 write), f-vector via
// broadcast b128 reads; rhs update uses lane's own Mc[j]. Back-sub via one
// LDS transpose dump + 64 shfl+fma steps. ~85 live VGPRs -> no spill.
__global__ void __launch_bounds__(64) k_solve(const float* __restrict__ sxxred,
        const int* __restrict__ counts, const float* __restrict__ pattern,
        float* __restrict__ params) {
    int bk = blockIdx.x;
    int lane = threadIdx.x;          // 0..63, one wave
    __shared__ __align__(16) float srow[2][64];
    __shared__ float smean[64];
    __shared__ __align__(16) float sT[64 * 65];   // transposed U for back-sub

    const float* pp = sxxred + (size_t)bk * PSTRIDE;
    int cnt = counts[bk];
    float inv = 1.0f / fmaxf((float)cnt, 1.0f);
    float mean_own = pp[4096 + lane] * inv;
    float pat_own = pattern[lane];
    float rhs_own = pat_own;
    smean[lane] = mean_own;
    __syncthreads();

    float Mc[64];    // column `lane` of cov
    #pragma unroll
    for (int r = 0; r < 64; ++r) {
        float s = pp[r * 64 + lane];             // coalesced
        float cov = s * inv - smean[r] * mean_own;
        Mc[r] = cov + ((r == lane) ? EPSV : 0.f);
    }

    // ---- forward elimination ----
    float pinv_own = 0.f;
    #pragma unroll
    for (int j = 0; j < 64; ++j) {
        srow[j & 1][lane] = Mc[j];               // publish row j (symmetry)
        __syncthreads();
        float pinv = 1.0f / srow[j & 1][j];      // broadcast read
        if (lane == j) pinv_own = pinv;
        float rhs_j = __shfl(rhs_own, j);
        if (lane > j) rhs_own = fmaf(-Mc[j] * pinv, rhs_j, rhs_own);
        #pragma unroll
        for (int i = (j + 1) >> 2; i < 16; ++i) {
            float4 rv = *((const float4*)&srow[j & 1][0] + i);
            float rvq[4] = {rv.x, rv.y, rv.z, rv.w};
            #pragma unroll
            for (int q = 0; q < 4; ++q) {
                int r = 4 * i + q;               // compile-time
                if (r > j)
                    Mc[r] = fmaf(-rvq[q] * pinv, Mc[j], Mc[r]);
            }
        }
        __syncthreads();
    }

    // ---- transpose dump: sT[lane][r] = U[r][lane] (2-way banks = free) ----
    #pragma unroll
    for (int r = 0; r < 64; ++r) sT[lane * 65 + r] = Mc[r];
    __syncthreads();

    // ---- back-substitution on distributed rhs ----
    #pragma unroll
    for (int jj = 0; jj < 64; ++jj) {
        int j = 63 - jj;
        float wj = __shfl(rhs_own * pinv_own, j);
        float u = sT[j * 65 + lane];             // U[lane][j]
        if (lane < j) rhs_own = fmaf(-u, wj, rhs_own);
    }
    float w_own = rhs_own * pinv_own;

    // ---- epilogue ----
    float dp = pat_own * w_own;
    float bias = mean_own * w_own;
    #pragma unroll
    for (int o = 32; o > 0; o >>= 1) {
        dp += __shfl_xor(dp, o);
        bias += __shfl_xor(bias, o);
    }
    float denom = sqrtf(dp);
    float valid = (cnt >= MINSZ) ? 1.0f : 0.0f;
    float scale = (denom > 0.f) ? (valid / denom) : 0.0f;
    params[bk * 66 + lane] = w_own * scale;
    if (lane == 0) {
        params[bk * 66 + 64] = bias * scale;
        params[bk * 66 + 65] = 0.f;
    }
}

// ---------------- K6: fused per-pixel score ----------------
__global__ void k_score(const float* __restrict__ x, const int* __restrict__ seg,
                        const float* __restrict__ params, float* __restrict__ out) {
    __shared__ float pw[NCLS][66];
    int t = threadIdx.x;
    int base = blockIdx.x * 256;
    int b = base / NPIX;
    for (int e = t; e < NCLS*66; e += 256)
        ((float*)pw)[e] = params[b*NCLS*66 + e];
    __syncthreads();

    int k = seg[base + t];
    int n = (base % NPIX) + t;
    const float* xb = x + (size_t)b * CH * NPIX + n;
    float a0 = 0.f, a1 = 0.f, a2 = 0.f, a3 = 0.f;
    #pragma unroll
    for (int c = 0; c < CH; c += 4) {
        a0 += xb[(size_t)(c+0) * NPIX] * pw[k][c+0];
        a1 += xb[(size_t)(c+1) * NPIX] * pw[k][c+1];
        a2 += xb[(size_t)(c+2) * NPIX] * pw[k][c+2];
        a3 += xb[(size_t)(c+3) * NPIX] * pw[k][c+3];
    }
    out[base + t] = (a0 + a1) + (a2 + a3) - pw[k][64];
}

// ---------------- launch ----------------
extern "C" void kernel_launch(void* const* d_in, const int* in_sizes, int n_in,
                              void* d_out, int out_size, void* d_ws, size_t ws_size,
                              hipStream_t stream) {
    const float* x       = (const float*)d_in[0];   // (B,C,H,W) fp32
    const float* pattern = (const float*)d_in[1];   // (C,) fp32
    const int*   seg     = (const int*)d_in[2];     // (B,H,W) int32
    float* out = (float*)d_out;

    unsigned short* gathered = (unsigned short*)d_ws;                  // B*N*CH bf16
    float* partials = (float*)(gathered + (size_t)BATCH * NPIX * CH);  // B*K*NCHUNK*PSTRIDE
    float* sxxred   = partials + (size_t)BATCH * NCLS * NCHUNK * PSTRIDE; // B*K*PSTRIDE
    float* params   = sxxred + (size_t)BATCH * NCLS * PSTRIDE;         // B*K*66
    int* hist      = (int*)(params + BATCH * NCLS * 66);               // NBLK*NCLS
    int* blockbase = hist + NBLK * NCLS;                               // NBLK*NCLS
    int* counts    = blockbase + NBLK * NCLS;                          // B*K
    int* offsets   = counts + BATCH * NCLS;                            // B*K

    k_hist   <<<NBLK,               256, 0, stream>>>(seg, hist);
    k_scanall<<<BATCH*NCLS,         256, 0, stream>>>(hist, counts, blockbase, offsets);
    k_scatter<<<NBLK,               256, 0, stream>>>(x, seg, blockbase, gathered);
    k_gemm   <<<BATCH*NCLS*NCHUNK,  256, 0, stream>>>(gathered, counts, offsets, partials);
    k_reduce <<<BATCH*NCLS*17,      256, 0, stream>>>(partials, sxxred);
    k_solve  <<<BATCH*NCLS,          64, 0, stream>>>(sxxred, counts, pattern, params);
    k_score  <<<NBLK,               256, 0, stream>>>(x, seg, params, out);
}